// Round 10
// baseline (149.848 us; speedup 1.0000x reference)
//
#include <hip/hip_runtime.h>

// x,y: [B=8, T=2048, C=1024] fp32.
// -mean(einsum('itj,itl->ijl', x, y)) ==
//   -(1/(B*C*C)) * sum_{rows} rowsum(x_row) * rowsum(y_row)
//
// Round 10: R6's streaming kernel (2048 x 256, 2 rows/wave, cross-lane work
// hoisted to wave end, 4-wave LDS fold) + fused last-block tail.
// R8/R9 root cause: winner condition (t&2047)==2047 only selects the LAST
// block when the ticket starts at 0 (mod 2048); the harness poisons d_ws to
// 0xAA -> winner fired ~682 blocks early. Fix: zero the 4-byte ticket with
// hipMemsetAsync each call (graph-capturable, proven in R5).
//  - publish block partial with atomic_exchange (RMW -> coherence point);
//  - __threadfence(); ticket fetch_add;
//  - winner = t == BLOCKS-1 (ticket zeroed) -> all 2047 others published;
//  - winner reads partials with fetch_add(p, 0.0) (RMW read, always fresh)
//    in a FIXED order -> bit-deterministic output.
#define N_C    1024
#define DENOM  (8.0 * 1024.0 * 1024.0)  // B*C*C

#define THREADS 256
#define BLOCKS  2048
#define WPB     (THREADS / 64)            // 4 waves/block
#define PPT     (BLOCKS / THREADS)        // 8 partials per thread in winner

__global__ __launch_bounds__(THREADS)
void corr_fused(const float* __restrict__ x,
                const float* __restrict__ y,
                double* __restrict__ partials,      // d_ws, BLOCKS doubles
                unsigned int* __restrict__ ticket,  // d_ws + BLOCKS*8, zeroed
                float* __restrict__ out) {
    const int lane = threadIdx.x & 63;
    const int w    = threadIdx.x >> 6;
    const int wave = blockIdx.x * WPB + w;          // 0..8191

    const size_t base = (size_t)(2 * wave) * N_C;   // 2 consecutive rows
    const float4* x0 = (const float4*)(x + base);
    const float4* y0 = (const float4*)(y + base);
    const float4* x1 = (const float4*)(x + base + N_C);
    const float4* y1 = (const float4*)(y + base + N_C);

    // Pure streaming: 16 coalesced float4 loads, vector adds, no shuffles.
    float4 ax = {0,0,0,0}, ay = {0,0,0,0}, bx = {0,0,0,0}, by = {0,0,0,0};
    #pragma unroll
    for (int k = 0; k < 4; ++k) {
        float4 vx0 = x0[lane + 64 * k];
        float4 vy0 = y0[lane + 64 * k];
        float4 vx1 = x1[lane + 64 * k];
        float4 vy1 = y1[lane + 64 * k];
        ax.x += vx0.x; ax.y += vx0.y; ax.z += vx0.z; ax.w += vx0.w;
        ay.x += vy0.x; ay.y += vy0.y; ay.z += vy0.z; ay.w += vy0.w;
        bx.x += vx1.x; bx.y += vx1.y; bx.z += vx1.z; bx.w += vx1.w;
        by.x += vy1.x; by.y += vy1.y; by.z += vy1.z; by.w += vy1.w;
    }
    float sx0 = (ax.x + ax.y) + (ax.z + ax.w);
    float sy0 = (ay.x + ay.y) + (ay.z + ay.w);
    float sx1 = (bx.x + bx.y) + (bx.z + bx.w);
    float sy1 = (by.x + by.y) + (by.z + by.w);

    // Four independent interleaved 64-lane butterflies (one latency tail).
    #pragma unroll
    for (int off = 32; off > 0; off >>= 1) {
        sx0 += __shfl_xor(sx0, off, 64);
        sy0 += __shfl_xor(sy0, off, 64);
        sx1 += __shfl_xor(sx1, off, 64);
        sy1 += __shfl_xor(sy1, off, 64);
    }

    // Fold the block's 4 wave-partials in LDS.
    __shared__ double sdata[WPB];
    __shared__ int won;
    if (lane == 0) sdata[w] = (double)sx0 * (double)sy0
                            + (double)sx1 * (double)sy1;
    __syncthreads();

    if (threadIdx.x == 0) {
        double bs = (sdata[0] + sdata[1]) + (sdata[2] + sdata[3]);
        // RMW store: performed at the coherence point, never stale.
        __hip_atomic_exchange(&partials[blockIdx.x], bs,
                              __ATOMIC_RELAXED, __HIP_MEMORY_SCOPE_AGENT);
        __threadfence();   // partial exchange performed before ticket add
        unsigned int t = __hip_atomic_fetch_add(ticket, 1u,
                           __ATOMIC_ACQ_REL, __HIP_MEMORY_SCOPE_AGENT);
        won = (t == BLOCKS - 1) ? 1 : 0;   // ticket zeroed -> truly last
    }
    __syncthreads();

    if (won) {
        // RMW reads: execute at the coherence point, see all 2048 exchanges
        // (each fenced before its ticket increment, all before ours).
        double acc = 0.0;
        #pragma unroll
        for (int k = 0; k < PPT; ++k)
            acc += __hip_atomic_fetch_add(
                       &partials[threadIdx.x + THREADS * k], 0.0,
                       __ATOMIC_RELAXED, __HIP_MEMORY_SCOPE_AGENT);
        #pragma unroll
        for (int off = 32; off > 0; off >>= 1)
            acc += __shfl_xor(acc, off, 64);
        if (lane == 0) sdata[w] = acc;    // safe: prior reads were before the
        __syncthreads();                  //   post-ticket barrier
        if (threadIdx.x == 0)
            out[0] = (float)(-((sdata[0] + sdata[1]) + (sdata[2] + sdata[3]))
                             / DENOM);
    }
}

extern "C" void kernel_launch(void* const* d_in, const int* in_sizes, int n_in,
                              void* d_out, int out_size, void* d_ws, size_t ws_size,
                              hipStream_t stream) {
    const float* x = (const float*)d_in[0];
    const float* y = (const float*)d_in[1];
    float* out = (float*)d_out;
    double* partials = (double*)d_ws;                        // 16 KiB
    unsigned int* ticket = (unsigned int*)((char*)d_ws + BLOCKS * 8);

    // Zero ONLY the ticket (4 bytes) each call; graph-capturable memset node.
    hipMemsetAsync(ticket, 0, sizeof(unsigned int), stream);
    corr_fused<<<BLOCKS, THREADS, 0, stream>>>(x, y, partials, ticket, out);
}

// Round 11
// 43.332 us; speedup vs baseline: 3.4581x; 3.4581x over previous
//
#include <hip/hip_runtime.h>

// x,y: [B=8, T=2048, C=1024] fp32.
// -mean(einsum('itj,itl->ijl', x, y)) ==
//   -(1/(B*C*C)) * sum_{rows} rowsum(x_row) * rowsum(y_row)
//
// Round 11: R6 streaming kernel (2048 x 256, 2 rows/wave) + fused last-block
// tail with ZERO cache-maintenance ops (R10's 5x regression = threadfence +
// acq_rel emitting L2 writeback/invalidate storms from 2048 blocks):
//  - partial published with RELAXED atomic_exchange (RMW -> executes at the
//    Infinity-Cache coherence point; no buffer_wb/inv emitted);
//  - raw `s_waitcnt vmcnt(0)` (thread 0 only) orders the exchange's
//    COMPLETION before the ticket RMW is issued — no fence, no cache ops;
//  - ticket fetch_add RELAXED; winner = t == BLOCKS-1 (ticket zeroed by a
//    4-byte hipMemsetAsync node each call — proven pattern from R5/R10);
//  - winner reads partials with RELAXED fetch_add(p, 0.0): IC-point RMW
//    reads, issued after all 2048 ticket increments were observed, hence
//    after all exchanges completed at IC. Fixed summation order ->
//    bit-deterministic output.
#define N_C    1024
#define DENOM  (8.0 * 1024.0 * 1024.0)  // B*C*C

#define THREADS 256
#define BLOCKS  2048
#define WPB     (THREADS / 64)            // 4 waves/block
#define PPT     (BLOCKS / THREADS)        // 8 partials per thread in winner

__global__ __launch_bounds__(THREADS)
void corr_fused(const float* __restrict__ x,
                const float* __restrict__ y,
                double* __restrict__ partials,      // d_ws, BLOCKS doubles
                unsigned int* __restrict__ ticket,  // d_ws + BLOCKS*8, zeroed
                float* __restrict__ out) {
    const int lane = threadIdx.x & 63;
    const int w    = threadIdx.x >> 6;
    const int wave = blockIdx.x * WPB + w;          // 0..8191

    const size_t base = (size_t)(2 * wave) * N_C;   // 2 consecutive rows
    const float4* x0 = (const float4*)(x + base);
    const float4* y0 = (const float4*)(y + base);
    const float4* x1 = (const float4*)(x + base + N_C);
    const float4* y1 = (const float4*)(y + base + N_C);

    // Pure streaming: 16 coalesced float4 loads, vector adds, no shuffles.
    float4 ax = {0,0,0,0}, ay = {0,0,0,0}, bx = {0,0,0,0}, by = {0,0,0,0};
    #pragma unroll
    for (int k = 0; k < 4; ++k) {
        float4 vx0 = x0[lane + 64 * k];
        float4 vy0 = y0[lane + 64 * k];
        float4 vx1 = x1[lane + 64 * k];
        float4 vy1 = y1[lane + 64 * k];
        ax.x += vx0.x; ax.y += vx0.y; ax.z += vx0.z; ax.w += vx0.w;
        ay.x += vy0.x; ay.y += vy0.y; ay.z += vy0.z; ay.w += vy0.w;
        bx.x += vx1.x; bx.y += vx1.y; bx.z += vx1.z; bx.w += vx1.w;
        by.x += vy1.x; by.y += vy1.y; by.z += vy1.z; by.w += vy1.w;
    }
    float sx0 = (ax.x + ax.y) + (ax.z + ax.w);
    float sy0 = (ay.x + ay.y) + (ay.z + ay.w);
    float sx1 = (bx.x + bx.y) + (bx.z + bx.w);
    float sy1 = (by.x + by.y) + (by.z + by.w);

    // Four independent interleaved 64-lane butterflies (one latency tail).
    #pragma unroll
    for (int off = 32; off > 0; off >>= 1) {
        sx0 += __shfl_xor(sx0, off, 64);
        sy0 += __shfl_xor(sy0, off, 64);
        sx1 += __shfl_xor(sx1, off, 64);
        sy1 += __shfl_xor(sy1, off, 64);
    }

    // Fold the block's 4 wave-partials in LDS.
    __shared__ double sdata[WPB];
    __shared__ int won;
    if (lane == 0) sdata[w] = (double)sx0 * (double)sy0
                            + (double)sx1 * (double)sy1;
    __syncthreads();

    if (threadIdx.x == 0) {
        double bs = (sdata[0] + sdata[1]) + (sdata[2] + sdata[3]);
        // Relaxed RMW store: executes at the IC coherence point, no cache ops.
        __hip_atomic_exchange(&partials[blockIdx.x], bs,
                              __ATOMIC_RELAXED, __HIP_MEMORY_SCOPE_AGENT);
        // Wait for the exchange to COMPLETE (ack) before issuing the ticket
        // RMW. Pure wave-local wait; emits no cache maintenance.
        asm volatile("s_waitcnt vmcnt(0)" ::: "memory");
        unsigned int t = __hip_atomic_fetch_add(ticket, 1u,
                           __ATOMIC_RELAXED, __HIP_MEMORY_SCOPE_AGENT);
        won = (t == BLOCKS - 1) ? 1 : 0;   // ticket zeroed -> truly last
    }
    __syncthreads();

    if (won) {
        // Relaxed RMW reads at IC: issued after all ticket increments were
        // observed; each partial's exchange completed at IC before its
        // ticket increment -> reads see every partial. Fixed order.
        double acc = 0.0;
        #pragma unroll
        for (int k = 0; k < PPT; ++k)
            acc += __hip_atomic_fetch_add(
                       &partials[threadIdx.x + THREADS * k], 0.0,
                       __ATOMIC_RELAXED, __HIP_MEMORY_SCOPE_AGENT);
        #pragma unroll
        for (int off = 32; off > 0; off >>= 1)
            acc += __shfl_xor(acc, off, 64);
        if (lane == 0) sdata[w] = acc;    // safe: prior use was before the
        __syncthreads();                  //   post-ticket barrier
        if (threadIdx.x == 0)
            out[0] = (float)(-((sdata[0] + sdata[1]) + (sdata[2] + sdata[3]))
                             / DENOM);
    }
}

extern "C" void kernel_launch(void* const* d_in, const int* in_sizes, int n_in,
                              void* d_out, int out_size, void* d_ws, size_t ws_size,
                              hipStream_t stream) {
    const float* x = (const float*)d_in[0];
    const float* y = (const float*)d_in[1];
    float* out = (float*)d_out;
    double* partials = (double*)d_ws;                        // 16 KiB
    unsigned int* ticket = (unsigned int*)((char*)d_ws + BLOCKS * 8);

    // Zero ONLY the 4-byte ticket each call; graph-capturable memset node.
    hipMemsetAsync(ticket, 0, sizeof(unsigned int), stream);
    corr_fused<<<BLOCKS, THREADS, 0, stream>>>(x, y, partials, ticket, out);
}

// Round 12
// 26.020 us; speedup vs baseline: 5.7589x; 1.6653x over previous
//
#include <hip/hip_runtime.h>

// x,y: [B=8, T=2048, C=1024] fp32.
// -mean(einsum('itj,itl->ijl', x, y)) ==
//   -(1/(B*C*C)) * sum_{rows} rowsum(x_row) * rowsum(y_row)
//
// FINAL (revert to round 6, the best measured config: 26.3 us).
// Two-kernel structure. Fusion was tried four ways and always lost:
//  - R5  (1024-thr fused + f64 atomics):      44.9 us (block-size tax)
//  - R8/R9 (ticket winner, unzeroed ticket):  WRONG (poisoned ws)
//  - R10 (threadfence + acq_rel tail):       149.8 us (L2 wb/inv storm)
//  - R11 (relaxed IC-RMW tail):               43.3 us (2048 same-address
//        ticket RMWs serialize at the Infinity Cache as blocks retire)
// k1: 2048 blocks x 256 thr, 2 rows/wave, pure float4 streaming (no
//     cross-lane ops in the hot path), 4 interleaved butterflies at wave
//     end, 4-wave LDS fold -> 2048 double partials.
// k2: single 64-lane wave, 16 double2 loads/lane, one butterfly.
// k1 streams 134 MB at ~6.1 TB/s effective (fillBuffer ceiling: 6.6-6.8);
// k2 + second graph node ~4 us. Roofline.
#define N_C    1024
#define DENOM  (8.0 * 1024.0 * 1024.0)  // B*C*C

#define THREADS 256
#define BLOCKS  2048
#define WPB     (THREADS / 64)            // 4 waves/block

__global__ __launch_bounds__(THREADS)
void corr_partial(const float* __restrict__ x,
                  const float* __restrict__ y,
                  double* __restrict__ partials) {
    const int lane = threadIdx.x & 63;
    const int w    = threadIdx.x >> 6;
    const int wave = blockIdx.x * WPB + w;          // 0..8191

    const size_t base = (size_t)(2 * wave) * N_C;   // 2 consecutive rows
    const float4* x0 = (const float4*)(x + base);
    const float4* y0 = (const float4*)(y + base);
    const float4* x1 = (const float4*)(x + base + N_C);
    const float4* y1 = (const float4*)(y + base + N_C);

    // Pure streaming: 16 coalesced float4 loads, vector adds, no shuffles.
    float4 ax = {0,0,0,0}, ay = {0,0,0,0}, bx = {0,0,0,0}, by = {0,0,0,0};
    #pragma unroll
    for (int k = 0; k < 4; ++k) {
        float4 vx0 = x0[lane + 64 * k];
        float4 vy0 = y0[lane + 64 * k];
        float4 vx1 = x1[lane + 64 * k];
        float4 vy1 = y1[lane + 64 * k];
        ax.x += vx0.x; ax.y += vx0.y; ax.z += vx0.z; ax.w += vx0.w;
        ay.x += vy0.x; ay.y += vy0.y; ay.z += vy0.z; ay.w += vy0.w;
        bx.x += vx1.x; bx.y += vx1.y; bx.z += vx1.z; bx.w += vx1.w;
        by.x += vy1.x; by.y += vy1.y; by.z += vy1.z; by.w += vy1.w;
    }
    float sx0 = (ax.x + ax.y) + (ax.z + ax.w);
    float sy0 = (ay.x + ay.y) + (ay.z + ay.w);
    float sx1 = (bx.x + bx.y) + (bx.z + bx.w);
    float sy1 = (by.x + by.y) + (by.z + by.w);

    // Four independent interleaved 64-lane butterflies (one latency tail).
    #pragma unroll
    for (int off = 32; off > 0; off >>= 1) {
        sx0 += __shfl_xor(sx0, off, 64);
        sy0 += __shfl_xor(sy0, off, 64);
        sx1 += __shfl_xor(sx1, off, 64);
        sy1 += __shfl_xor(sy1, off, 64);
    }

    // Fold the block's 4 wave-partials: 32 B LDS, one cheap 4-wave barrier.
    __shared__ double sdata[WPB];
    if (lane == 0) sdata[w] = (double)sx0 * (double)sy0
                            + (double)sx1 * (double)sy1;
    __syncthreads();
    if (threadIdx.x == 0)
        partials[blockIdx.x] = (sdata[0] + sdata[1]) + (sdata[2] + sdata[3]);
}

__global__ __launch_bounds__(64)
void corr_final_reduce(const double* __restrict__ partials,
                       float* __restrict__ out) {
    const int lane = threadIdx.x;          // single wave, 64 lanes
    // 2048 doubles / 64 lanes = 32 doubles = 16 double2 loads per lane.
    const double2* p = (const double2*)partials;
    double acc = 0.0;
    #pragma unroll
    for (int k = 0; k < 16; ++k) {
        double2 v = p[lane + 64 * k];      // coalesced, all 16 in flight
        acc += v.x + v.y;
    }
    #pragma unroll
    for (int off = 32; off > 0; off >>= 1)
        acc += __shfl_xor(acc, off, 64);
    if (lane == 0) out[0] = (float)(-acc / DENOM);
}

extern "C" void kernel_launch(void* const* d_in, const int* in_sizes, int n_in,
                              void* d_out, int out_size, void* d_ws, size_t ws_size,
                              hipStream_t stream) {
    const float* x = (const float*)d_in[0];
    const float* y = (const float*)d_in[1];
    float* out = (float*)d_out;
    double* partials = (double*)d_ws;   // BLOCKS * 8 = 16 KiB scratch

    corr_partial<<<BLOCKS, THREADS, 0, stream>>>(x, y, partials);
    corr_final_reduce<<<1, 64, 0, stream>>>(partials, out);
}